// Round 15
// baseline (248.197 us; speedup 1.0000x reference)
//
#include <hip/hip_runtime.h>
#include <cmath>

// InvariantPointAttention, N=768, H=12, D=16, NQP=4, NVP=8, NODE=384, EDGE=128.
// R15 = R14 + 2-deep register prefetch (rA/rB) in k_fused with the R8-proven
// staging pattern (paired 16B loads, b128 ds_writes). Issue-to-wait distance
// ~2 iterations > HBM latency -> no exposed stall.

namespace {

constexpr int NN = 768;
constexpr int NH = 12;

constexpr float S3 = 0.5773502691896258f;        // 3^-0.5
constexpr float C1 = 0.25f * S3;
constexpr float C2 = 0.23570226039551584f * S3;
constexpr float C3 = 0.11785113019775792f * S3;

typedef float f32x4 __attribute__((ext_vector_type(4)));
typedef short bf16x8 __attribute__((ext_vector_type(8)));
typedef unsigned int u32x4 __attribute__((ext_vector_type(4)));
typedef unsigned int u32x2 __attribute__((ext_vector_type(2)));
typedef _Float16 f16x2 __attribute__((ext_vector_type(2)));

#define LGKM0 asm volatile("s_waitcnt lgkmcnt(0)" ::: "memory")
#define SCHED0 __builtin_amdgcn_sched_barrier(0)

__device__ inline unsigned cvt_pk_bf16(float lo, float hi) {
  unsigned r;
  asm volatile("v_cvt_pk_bf16_f32 %0, %1, %2" : "=v"(r) : "v"(lo), "v"(hi));
  return r;
}

__device__ inline float fdot2(unsigned a, unsigned b, float c) {
#if __has_builtin(__builtin_amdgcn_fdot2)
  return __builtin_amdgcn_fdot2(__builtin_bit_cast(f16x2, a),
                                __builtin_bit_cast(f16x2, b), c, false);
#else
  union U { unsigned u; _Float16 h[2]; } x, y;
  x.u = a; y.u = b;
  return c + (float)x.h[0] * (float)y.h[0] + (float)x.h[1] * (float)y.h[1];
#endif
}

__device__ inline u32x2 tr_read(unsigned addr) {
  u32x2 d;
  asm volatile("ds_read_b64_tr_b16 %0, %1" : "=v"(d) : "v"(addr));
  return d;
}

__device__ inline f32x4 mfma16(u32x2 a, u32x2 b, f32x4 c) {
  asm volatile("v_mfma_f32_16x16x16_bf16 %0, %1, %2, %0"
               : "+v"(c) : "v"(a), "v"(b));
  return c;
}

__device__ inline unsigned pkf16(float a, float b) {
  union U { _Float16 h[2]; unsigned u; } x;
  x.h[0] = (_Float16)a; x.h[1] = (_Float16)b;
  return x.u;
}

// ---------------------------------------------------------------- k_proj ----
__global__ __launch_bounds__(288) void k_proj(const float* __restrict__ node,
    const float* __restrict__ Wqkv, const float* __restrict__ Wvqk,
    const float* __restrict__ Wvv, float* __restrict__ proj) {
  __shared__ __align__(16) float nl[2][384];
  const int i0 = blockIdx.x * 2;
  const int tid = threadIdx.x;
  for (int idx = tid; idx < 2 * 384; idx += 288)
    ((float*)nl)[idx] = node[(size_t)i0 * 384 + idx];
  __syncthreads();
  const int c0 = tid * 4;
  const float* W; int ld, col;
  if (c0 < 576)      { W = Wqkv; ld = 576; col = c0; }
  else if (c0 < 864) { W = Wvqk; ld = 288; col = c0 - 576; }
  else               { W = Wvv;  ld = 288; col = c0 - 864; }
  float4 acc[2];
#pragma unroll
  for (int r = 0; r < 2; ++r) acc[r] = make_float4(0.f, 0.f, 0.f, 0.f);
#pragma unroll 4
  for (int k = 0; k < 384; ++k) {
    const float4 w4 = *(const float4*)&W[(size_t)k * ld + col];
#pragma unroll
    for (int r = 0; r < 2; ++r) {
      const float nv = nl[r][k];
      acc[r].x += nv * w4.x; acc[r].y += nv * w4.y;
      acc[r].z += nv * w4.z; acc[r].w += nv * w4.w;
    }
  }
#pragma unroll
  for (int r = 0; r < 2; ++r)
    *(float4*)&proj[(size_t)(i0 + r) * 1152 + c0] = acc[r];
}

// ---------------------------------------------------------------- k_geom ----
__global__ __launch_bounds__(256) void k_geom(const float* __restrict__ proj,
    const float* __restrict__ R, const float* __restrict__ t,
    const float* __restrict__ Webias,
    unsigned* __restrict__ Bph, unsigned* __restrict__ Sgh,
    float* __restrict__ V, unsigned* __restrict__ WbP) {
  const int gid = blockIdx.x * 256 + threadIdx.x;
  if (blockIdx.x == 0) {
    const int tid = threadIdx.x;
    const int lane = tid & 63, kk = tid >> 6;
    const int colB = lane & 15, gB = lane >> 4;
    u32x4 wv;
#pragma unroll
    for (int e = 0; e < 4; ++e) {
      const int d = kk * 32 + gB * 8 + 2 * e;
      const float lo = (colB < 12) ? S3 * Webias[d * 12 + colB] : 0.f;
      const float hi = (colB < 12) ? S3 * Webias[(d + 1) * 12 + colB] : 0.f;
      wv[e] = cvt_pk_bf16(lo, hi);
    }
    *(u32x4*)&WbP[(size_t)tid * 4] = wv;
  }
  if (gid >= NN * NH) return;
  const int n = gid / NH, h = gid % NH;
  const float* pr = proj + (size_t)n * 1152;
  const float* Rn = R + n * 9;
  const float t0 = t[n * 3 + 0], t1 = t[n * 3 + 1], t2 = t[n * 3 + 2];
  const size_t hn = (size_t)h * NN + n;
  unsigned* bp = Bph + ((size_t)n * NH + h) * 16;   // j-major
  unsigned* sg = Sgh + ((size_t)n * NH + h) * 16;
#pragma unroll
  for (int m = 0; m < 8; ++m) {
    bp[m] = pkf16(C1 * pr[(12 + h) * 16 + 2 * m], C1 * pr[(12 + h) * 16 + 2 * m + 1]);
    sg[m] = pkf16(pr[h * 16 + 2 * m], pr[h * 16 + 2 * m + 1]);
    V[hn * 40 + 2 * m]     = pr[(24 + h) * 16 + 2 * m];
    V[hn * 40 + 2 * m + 1] = pr[(24 + h) * 16 + 2 * m + 1];
  }
  float gq[12], gk[12];
  float qs = 0.f, ks = 0.f;
#pragma unroll
  for (int p = 0; p < 4; ++p) {
    {
      const float vx = pr[576 + (h * 4 + p) * 3 + 0];
      const float vy = pr[576 + (h * 4 + p) * 3 + 1];
      const float vz = pr[576 + (h * 4 + p) * 3 + 2];
      const float g0 = Rn[0] * vx + Rn[1] * vy + Rn[2] * vz + t0;
      const float g1 = Rn[3] * vx + Rn[4] * vy + Rn[5] * vz + t1;
      const float g2 = Rn[6] * vx + Rn[7] * vy + Rn[8] * vz + t2;
      gq[p * 3 + 0] = g0; gq[p * 3 + 1] = g1; gq[p * 3 + 2] = g2;
      qs += g0 * g0 + g1 * g1 + g2 * g2;
    }
    {
      const float vx = pr[576 + ((12 + h) * 4 + p) * 3 + 0];
      const float vy = pr[576 + ((12 + h) * 4 + p) * 3 + 1];
      const float vz = pr[576 + ((12 + h) * 4 + p) * 3 + 2];
      const float g0 = Rn[0] * vx + Rn[1] * vy + Rn[2] * vz + t0;
      const float g1 = Rn[3] * vx + Rn[4] * vy + Rn[5] * vz + t1;
      const float g2 = Rn[6] * vx + Rn[7] * vy + Rn[8] * vz + t2;
      gk[p * 3 + 0] = g0; gk[p * 3 + 1] = g1; gk[p * 3 + 2] = g2;
      ks += g0 * g0 + g1 * g1 + g2 * g2;
    }
  }
#pragma unroll
  for (int m = 0; m < 6; ++m) {
    bp[8 + m] = pkf16(C2 * gq[2 * m], C2 * gq[2 * m + 1]);
    sg[8 + m] = pkf16(gk[2 * m], gk[2 * m + 1]);
  }
  bp[14] = pkf16(-C3 * qs, 1.0f);
  sg[14] = pkf16(1.0f, -C3 * ks);
  bp[15] = 0u; sg[15] = 0u;
#pragma unroll
  for (int p = 0; p < 8; ++p) {
    const float vx = pr[864 + (h * 8 + p) * 3 + 0];
    const float vy = pr[864 + (h * 8 + p) * 3 + 1];
    const float vz = pr[864 + (h * 8 + p) * 3 + 2];
    V[hn * 40 + 16 + p * 3 + 0] = Rn[0] * vx + Rn[1] * vy + Rn[2] * vz + t0;
    V[hn * 40 + 16 + p * 3 + 1] = Rn[3] * vx + Rn[4] * vy + Rn[5] * vz + t1;
    V[hn * 40 + 16 + p * 3 + 2] = Rn[6] * vx + Rn[7] * vy + Rn[8] * vz + t2;
  }
}

// --------------------------------------------------------------- k_fused ----
// As R14, but 2-deep register prefetch: rA/rB hold tiles t and t+1; loads
// for t+2 are issued right after store8(t) -> issue-to-wait ~2 iterations.
__global__ __launch_bounds__(256, 3) void k_fused(
    const float* __restrict__ edge, const unsigned* __restrict__ WbP,
    const unsigned* __restrict__ Bph, const unsigned* __restrict__ Sgh,
    unsigned* __restrict__ pT2, float* __restrict__ m_t2,
    float* __restrict__ eout, float* __restrict__ msm,
    float* __restrict__ linv) {
  __shared__ __align__(16) unsigned char wreg[4][4224];   // 16.9 KB total
  const int i = blockIdx.x;
  const int tid = threadIdx.x;
  const int lane = tid & 63;
  const int w = __builtin_amdgcn_readfirstlane(tid >> 6);
  const int g = lane >> 4;          // 0..3
  const int c16 = lane & 15;        // h (logits/C-col), j (eb A-row), d' (PV)
  const int hc = c16 < 12 ? c16 : 11;

  unsigned short* etSw = (unsigned short*)&wreg[w][0];
  const unsigned etbase =
      (unsigned)(uintptr_t)(__attribute__((address_space(3))) unsigned char*)&wreg[w][0];

  bf16x8 wbfrag[4];
#pragma unroll
  for (int kk = 0; kk < 4; ++kk)
    wbfrag[kk] = __builtin_bit_cast(bf16x8,
        *(const u32x4*)&WbP[(size_t)(kk * 64 + lane) * 4]);

  const unsigned* sgp = Sgh + ((size_t)i * NH + hc) * 16;
  const u32x4 sg0 = *(const u32x4*)(sgp + 0);
  const u32x4 sg1 = *(const u32x4*)(sgp + 4);
  const u32x4 sg2 = *(const u32x4*)(sgp + 8);
  const u32x4 sg3 = *(const u32x4*)(sgp + 12);

  float m = -3.0e38f;
  float lsum = 0.f;
  f32x4 acc[8];
#pragma unroll
  for (int dt = 0; dt < 8; ++dt) acc[dt] = (f32x4){0.f, 0.f, 0.f, 0.f};

  float4 rA[8], rB[8];
  auto load8 = [&](int t, float4* r) {
    const int jw = t * 64 + w * 16;
#pragma unroll
    for (int q = 0; q < 4; ++q) {
      const int f8 = lane + 64 * q;
      const int j = f8 >> 4, c8 = f8 & 15;
      const float* gp = &edge[((size_t)(i * NN + jw + j)) * 128 + c8 * 8];
      r[2 * q]     = *(const float4*)gp;
      r[2 * q + 1] = *(const float4*)(gp + 4);
    }
  };
  auto store8 = [&](const float4* r) {
#pragma unroll
    for (int q = 0; q < 4; ++q) {
      const int f8 = lane + 64 * q;
      const int j = f8 >> 4, c8 = f8 & 15;
      u32x4 pk;
      pk.x = cvt_pk_bf16(r[2 * q].x,     r[2 * q].y);
      pk.y = cvt_pk_bf16(r[2 * q].z,     r[2 * q].w);
      pk.z = cvt_pk_bf16(r[2 * q + 1].x, r[2 * q + 1].y);
      pk.w = cvt_pk_bf16(r[2 * q + 1].z, r[2 * q + 1].w);
      *(u32x4*)&etSw[(c8 >> 1) * 264 + j * 16 + 8 * (c8 & 1)] = pk;
    }
  };

  load8(0, rA);
  load8(1, rB);

#pragma unroll 1
  for (int t = 0; t < 12; ++t) {
    const int tw = t * 4 + w;
    LGKM0;                       // prior tile's tr reads drained before overwrite
    if (t & 1) store8(rB); else store8(rA);   // waits only this buffer's vmcnt
    SCHED0;                      // pin ds_writes before all later LDS consumers
    if (t + 2 < 12) {
      if (t & 1) load8(t + 2, rB); else load8(t + 2, rA);
    }

    // ---- eb MFMA (feeds logits only at the END -> off the fdot2 path)
    f32x4 ebacc = {0.f, 0.f, 0.f, 0.f};
#pragma unroll
    for (int kk = 0; kk < 4; ++kk) {
      const int dt = 2 * kk + (g >> 1);
      const bf16x8 a = *(const bf16x8*)&etSw[dt * 264 + c16 * 16 + 8 * (g & 1)];
      ebacc = __builtin_amdgcn_mfma_f32_16x16x32_bf16(a, wbfrag[kk], ebacc, 0, 0, 0);
    }

    // ---- logits: fdot2 chain starts from 0 (L2 loads overlap eb MFMAs)
    float lg[4];
#pragma unroll
    for (int r = 0; r < 4; ++r) {
      const unsigned* bpp = Bph + ((size_t)(tw * 16 + 4 * g + r) * NH + hc) * 16;
      const u32x4 b0 = *(const u32x4*)(bpp + 0);
      const u32x4 b1 = *(const u32x4*)(bpp + 4);
      const u32x4 b2 = *(const u32x4*)(bpp + 8);
      const u32x4 b3 = *(const u32x4*)(bpp + 12);
      float a = fdot2(b0.x, sg0.x, 0.f);
      a = fdot2(b0.y, sg0.y, a);
      a = fdot2(b0.z, sg0.z, a); a = fdot2(b0.w, sg0.w, a);
      a = fdot2(b1.x, sg1.x, a); a = fdot2(b1.y, sg1.y, a);
      a = fdot2(b1.z, sg1.z, a); a = fdot2(b1.w, sg1.w, a);
      a = fdot2(b2.x, sg2.x, a); a = fdot2(b2.y, sg2.y, a);
      a = fdot2(b2.z, sg2.z, a); a = fdot2(b2.w, sg2.w, a);
      a = fdot2(b3.x, sg3.x, a); a = fdot2(b3.y, sg3.y, a);
      a = fdot2(b3.z, sg3.z, a);
      lg[r] = a + ebacc[r];
    }

    // ---- defer-max online softmax (per-lane h; m uniform across g-lanes)
    const float lmax = fmaxf(fmaxf(lg[0], lg[1]), fmaxf(lg[2], lg[3]));
    if (__any(lmax > m + 6.f)) {
      float tm = lmax;
      tm = fmaxf(tm, __shfl_xor(tm, 16, 64));
      tm = fmaxf(tm, __shfl_xor(tm, 32, 64));
      const float mn = fmaxf(m, tm);
      const float f = __expf(m - mn);
      m = mn;
      lsum *= f;
      float fr[4];
#pragma unroll
      for (int r = 0; r < 4; ++r) fr[r] = __shfl(f, 4 * g + r, 64);
#pragma unroll
      for (int dt = 0; dt < 8; ++dt) {
        acc[dt][0] *= fr[0]; acc[dt][1] *= fr[1];
        acc[dt][2] *= fr[2]; acc[dt][3] *= fr[3];
      }
    }
    float p0 = __expf(lg[0] - m), p1 = __expf(lg[1] - m);
    float p2 = __expf(lg[2] - m), p3 = __expf(lg[3] - m);
    lsum += (p0 + p1) + (p2 + p3);
    const unsigned pk0 = cvt_pk_bf16(p0, p1);
    const unsigned pk1 = cvt_pk_bf16(p2, p3);
    if (c16 < 12) {
      u32x2 pp; pp.x = pk0; pp.y = pk1;
      *(u32x2*)&pT2[((size_t)c16 * NN + i) * 384 + tw * 8 + g * 2] = pp;
      if (g == 0) m_t2[((size_t)c16 * NN + i) * 48 + tw] = m;
    }

    // ---- PV: A = p in regs; B = E via tr reads, 2 batches of 4
    u32x2 apk; apk.x = pk0; apk.y = pk1;
    u32x2 bfr[4];
#pragma unroll
    for (int half = 0; half < 2; ++half) {
#pragma unroll
      for (int q = 0; q < 4; ++q)
        bfr[q] = tr_read(etbase + (unsigned)((half * 4 + q) * 528 + g * 128 + c16 * 8));
      LGKM0; SCHED0;
#pragma unroll
      for (int q = 0; q < 4; ++q)
        acc[half * 4 + q] = mfma16(apk, bfr[q], acc[half * 4 + q]);
    }
  }

  // ---- tail: write own slab (etS dead after final LGKM0), then merge
  {
    unsigned short* OshW = (unsigned short*)&wreg[w][0];
#pragma unroll
    for (int dt = 0; dt < 8; ++dt) {
      u32x2 pkk;
      pkk.x = cvt_pk_bf16(acc[dt][0], acc[dt][1]);
      pkk.y = cvt_pk_bf16(acc[dt][2], acc[dt][3]);
      *(u32x2*)&OshW[dt * 256 + c16 * 16 + g * 4] = pkk;
    }
    float ls = lsum;
    ls += __shfl_xor(ls, 16, 64);
    ls += __shfl_xor(ls, 32, 64);
    if (lane < 16) {
      *(float*)&wreg[w][4096 + lane * 4] = m;
      *(float*)&wreg[w][4160 + lane * 4] = ls;
    }
  }
  __syncthreads();
  for (int idx = tid; idx < 12 * 128; idx += 256) {
    const int h = idx >> 7, d = idx & 127;
    const int dt = d >> 4, dp = d & 15;
    float mv[4], lv[4], Ov[4];
#pragma unroll
    for (int w2 = 0; w2 < 4; ++w2) {
      mv[w2] = *(const float*)&wreg[w2][4096 + h * 4];
      lv[w2] = *(const float*)&wreg[w2][4160 + h * 4];
      const unsigned short us =
          *(const unsigned short*)&wreg[w2][(dt * 256 + dp * 16 + h) * 2];
      Ov[w2] = __uint_as_float(((unsigned)us) << 16);
    }
    const float mb = fmaxf(fmaxf(mv[0], mv[1]), fmaxf(mv[2], mv[3]));
    const float f0 = __expf(mv[0] - mb), f1 = __expf(mv[1] - mb);
    const float f2 = __expf(mv[2] - mb), f3 = __expf(mv[3] - mb);
    const float lb = lv[0] * f0 + lv[1] * f1 + lv[2] * f2 + lv[3] * f3;
    const float O = Ov[0] * f0 + Ov[1] * f1 + Ov[2] * f2 + Ov[3] * f3;
    eout[(size_t)i * 1536 + h * 128 + d] = O / lb;
    if (d == 0) {
      msm[(size_t)h * NN + i] = mb;
      linv[(size_t)h * NN + i] = 1.0f / lb;
    }
  }
}

// ---------------------------------------------------------------- k_scav ----
__global__ __launch_bounds__(320) void k_scav(const unsigned* __restrict__ pT2,
    const float* __restrict__ m_t2, const float* __restrict__ msm,
    const float* __restrict__ linv, const float* __restrict__ V,
    const float* __restrict__ R, const float* __restrict__ t,
    float* __restrict__ combX) {
  __shared__ __align__(16) float At[64][20];
  __shared__ __align__(16) float Vt[64][40];
  __shared__ __align__(16) float red[320 * 8];
  __shared__ __align__(16) float fac[16][48];
  __shared__ __align__(16) float sc[16][40];
  __shared__ float rinv[16][9];
  __shared__ float tl[16][3];
  const int i0 = blockIdx.x * 16;
  const int h  = blockIdx.y;
  const int tid = threadIdx.x;
  const int js = tid / 80, rem = tid % 80;
  const int rg = rem / 20, cp = rem % 20;

  if (tid < 16) {
    const int i = i0 + tid;
    const float* Rn = R + i * 9;
    const float r00 = Rn[0], r01 = Rn[1], r02 = Rn[2];
    const float r10 = Rn[3], r11 = Rn[4], r12 = Rn[5];
    const float r20 = Rn[6], r21 = Rn[7], r22 = Rn[8];
    const float det = r00 * (r11 * r22 - r12 * r21)
                    - r01 * (r10 * r22 - r12 * r20)
                    + r02 * (r10 * r21 - r11 * r20);
    const float id = 1.0f / det;
    rinv[tid][0] = (r11 * r22 - r12 * r21) * id;
    rinv[tid][1] = (r02 * r21 - r01 * r22) * id;
    rinv[tid][2] = (r01 * r12 - r02 * r11) * id;
    rinv[tid][3] = (r12 * r20 - r10 * r22) * id;
    rinv[tid][4] = (r00 * r22 - r02 * r20) * id;
    rinv[tid][5] = (r02 * r10 - r00 * r12) * id;
    rinv[tid][6] = (r10 * r21 - r11 * r20) * id;
    rinv[tid][7] = (r01 * r20 - r00 * r21) * id;
    rinv[tid][8] = (r00 * r11 - r01 * r10) * id;
    tl[tid][0] = t[i * 3 + 0]; tl[tid][1] = t[i * 3 + 1]; tl[tid][2] = t[i * 3 + 2];
  }
  for (int idx = tid; idx < 768; idx += 320) {
    const int r = idx / 48, tw = idx % 48;
    const size_t hi = (size_t)h * NN + i0 + r;
    fac[r][tw] = __expf(m_t2[hi * 48 + tw] - msm[hi]) * linv[hi];
  }

  float2 a0 = {0.f, 0.f}, a1 = {0.f, 0.f}, a2 = {0.f, 0.f}, a3 = {0.f, 0.f};
  for (int jt = 0; jt < 12; ++jt) {
    __syncthreads();
    for (int idx = tid; idx < 256; idx += 320) {
      const int r = idx >> 4, q = idx & 15;
      const u32x2 v = *(const u32x2*)
          &pT2[((size_t)h * NN + i0 + r) * 384 + jt * 32 + q * 2];
      const float fc = fac[r][jt * 4 + (q >> 2)];
      At[q * 4 + 0][r] = __uint_as_float(v.x << 16) * fc;
      At[q * 4 + 1][r] = __uint_as_float(v.x & 0xffff0000u) * fc;
      At[q * 4 + 2][r] = __uint_as_float(v.y << 16) * fc;
      At[q * 4 + 3][r] = __uint_as_float(v.y & 0xffff0000u) * fc;
    }
    for (int idx = tid; idx < 2560; idx += 320) {
      const int jj = idx / 40, c = idx % 40;
      Vt[jj][c] = V[((size_t)h * NN + jt * 64 + jj) * 40 + c];
    }
    __syncthreads();
#pragma unroll 4
    for (int s = 0; s < 16; ++s) {
      const int jj = js * 16 + s;
      const float4 a4 = *(const float4*)&At[jj][rg * 4];
      const float2 b2 = *(const float2*)&Vt[jj][cp * 2];
      a0.x += a4.x * b2.x; a0.y += a4.x * b2.y;
      a1.x += a4.y * b2.x; a1.y += a4.y * b2.y;
      a2.x += a4.z * b2.x; a2.y += a4.z * b2.y;
      a3.x += a4.w * b2.x; a3.y += a4.w * b2.y;
    }
  }
  __syncthreads();
  *(float4*)&red[tid * 8 + 0] = make_float4(a0.x, a0.y, a1.x, a1.y);
  *(float4*)&red[tid * 8 + 4] = make_float4(a2.x, a2.y, a3.x, a3.y);
  __syncthreads();
  if (tid < 80) {
    const int rg2 = tid / 20, cp2 = tid % 20;
    float4 s0 = make_float4(0.f, 0.f, 0.f, 0.f), s1 = s0;
#pragma unroll
    for (int q = 0; q < 4; ++q) {
      const float4 r0 = *(const float4*)&red[(tid + q * 80) * 8 + 0];
      const float4 r1 = *(const float4*)&red[(tid + q * 80) * 8 + 4];
      s0.x += r0.x; s0.y += r0.y; s0.z += r0.z; s0.w += r0.w;
      s1.x += r1.x; s1.y += r1.y; s1.z += r1.z; s1.w += r1.w;
    }
    sc[rg2 * 4 + 0][cp2 * 2] = s0.x; sc[rg2 * 4 + 0][cp2 * 2 + 1] = s0.y;
    sc[rg2 * 4 + 1][cp2 * 2] = s0.z; sc[rg2 * 4 + 1][cp2 * 2 + 1] = s0.w;
    sc[rg2 * 4 + 2][cp2 * 2] = s1.x; sc[rg2 * 4 + 2][cp2 * 2 + 1] = s1.y;
    sc[rg2 * 4 + 3][cp2 * 2] = s1.z; sc[rg2 * 4 + 3][cp2 * 2 + 1] = s1.w;
  }
  __syncthreads();
  for (int idx = tid; idx < 768; idx += 320) {
    const int r = idx / 48, c = idx % 48;
    const int i = i0 + r;
    float val; int col;
    if (c < 16) {
      val = sc[r][c];
      col = h * 16 + c;
    } else if (c < 40) {
      const int s = c - 16, p = s / 3, x = s % 3;
      const float a0v = sc[r][16 + p * 3 + 0] - tl[r][0];
      const float a1v = sc[r][16 + p * 3 + 1] - tl[r][1];
      const float a2v = sc[r][16 + p * 3 + 2] - tl[r][2];
      val = rinv[r][x * 3 + 0] * a0v + rinv[r][x * 3 + 1] * a1v
          + rinv[r][x * 3 + 2] * a2v;
      col = 192 + h * 24 + s;
    } else {
      const int p = c - 40;
      const float a0v = sc[r][16 + p * 3 + 0] - tl[r][0];
      const float a1v = sc[r][16 + p * 3 + 1] - tl[r][1];
      const float a2v = sc[r][16 + p * 3 + 2] - tl[r][2];
      const float l0 = rinv[r][0] * a0v + rinv[r][1] * a1v + rinv[r][2] * a2v;
      const float l1 = rinv[r][3] * a0v + rinv[r][4] * a1v + rinv[r][5] * a2v;
      const float l2 = rinv[r][6] * a0v + rinv[r][7] * a1v + rinv[r][8] * a2v;
      val = sqrtf(l0 * l0 + l1 * l1 + l2 * l2);
      col = 480 + h * 8 + p;
    }
    combX[(size_t)i * 576 + col] = val;
  }
}

// -------------------------------------------------------------- k_finalA ----
__global__ __launch_bounds__(256) void k_finalA(
    const float* __restrict__ eout, const float* __restrict__ combX,
    const float* __restrict__ Wfin, float* __restrict__ partial) {
  __shared__ __align__(16) float cl[64][36];
  __shared__ __align__(16) float wl[32][68];
  const int i0 = blockIdx.x * 64;
  const int c0 = blockIdx.y * 64;
  const int k0 = blockIdx.z * 192;
  const float* src; int stride, koff;
  if (blockIdx.z < 8) { src = eout;  stride = 1536; koff = k0; }
  else                { src = combX; stride = 576;  koff = k0 - 1536; }
  const int tid = threadIdx.x;
  const int cq = tid & 15, rq = tid >> 4;
  float4 acc[4];
#pragma unroll
  for (int r = 0; r < 4; ++r) acc[r] = make_float4(0.f, 0.f, 0.f, 0.f);
  for (int sub = 0; sub < 6; ++sub) {
    const int kc = sub * 32;
    __syncthreads();
#pragma unroll
    for (int half = 0; half < 2; ++half) {
      const int qi = tid + half * 256;
      const int r = qi >> 3, kq = qi & 7;
      *(float4*)&cl[r][kq * 4] =
          *(const float4*)&src[(size_t)(i0 + r) * stride + koff + kc + kq * 4];
      const int kk = qi >> 4, cc = qi & 15;
      *(float4*)&wl[kk][cc * 4] =
          *(const float4*)&Wfin[(size_t)(k0 + kc + kk) * 384 + c0 + cc * 4];
    }
    __syncthreads();
#pragma unroll
    for (int k4 = 0; k4 < 8; ++k4) {
      float4 a[4], wv[4];
#pragma unroll
      for (int r = 0; r < 4; ++r) a[r] = *(const float4*)&cl[rq * 4 + r][k4 * 4];
#pragma unroll
      for (int q = 0; q < 4; ++q) wv[q] = *(const float4*)&wl[k4 * 4 + q][cq * 4];
#pragma unroll
      for (int r = 0; r < 4; ++r) {
        acc[r].x += a[r].x * wv[0].x + a[r].y * wv[1].x + a[r].z * wv[2].x + a[r].w * wv[3].x;
        acc[r].y += a[r].x * wv[0].y + a[r].y * wv[1].y + a[r].z * wv[2].y + a[r].w * wv[3].y;
        acc[r].z += a[r].x * wv[0].z + a[r].y * wv[1].z + a[r].z * wv[2].z + a[r].w * wv[3].z;
        acc[r].w += a[r].x * wv[0].w + a[r].y * wv[1].w + a[r].z * wv[2].w + a[r].w * wv[3].w;
      }
    }
  }
#pragma unroll
  for (int r = 0; r < 4; ++r)
    *(float4*)&partial[((size_t)blockIdx.z * NN + i0 + rq * 4 + r) * 384 + c0 + cq * 4] = acc[r];
}

// -------------------------------------------------------------- k_finalB ----
__global__ __launch_bounds__(256) void k_finalB(const float* __restrict__ node,
    const float* __restrict__ partial, const float* __restrict__ bfin,
    float* __restrict__ out) {
  const int gid = blockIdx.x * 256 + threadIdx.x;
  const int i = gid / 96, cq = gid % 96;
  float4 v = *(const float4*)&node[(size_t)i * 384 + cq * 4];
  const float4 b = *(const float4*)&bfin[cq * 4];
  v.x += b.x; v.y += b.y; v.z += b.z; v.w += b.w;
#pragma unroll
  for (int s = 0; s < 11; ++s) {
    const float4 p = *(const float4*)&partial[((size_t)s * NN + i) * 384 + cq * 4];
    v.x += p.x; v.y += p.y; v.z += p.z; v.w += p.w;
  }
  *(float4*)&out[(size_t)i * 384 + cq * 4] = v;
}

}  // namespace

extern "C" void kernel_launch(void* const* d_in, const int* in_sizes, int n_in,
                              void* d_out, int out_size, void* d_ws, size_t ws_size,
                              hipStream_t stream) {
  const float* node   = (const float*)d_in[0];
  const float* edge   = (const float*)d_in[1];
  const float* R      = (const float*)d_in[2];
  const float* t      = (const float*)d_in[3];
  const float* Wqkv   = (const float*)d_in[4];
  const float* Wvqk   = (const float*)d_in[5];
  const float* Wvv    = (const float*)d_in[6];
  const float* Webias = (const float*)d_in[7];
  const float* Wfin   = (const float*)d_in[8];
  const float* bfin   = (const float*)d_in[9];
  float* out = (float*)d_out;

  float* ws = (float*)d_ws;
  float*    proj = ws;                       // 884736
  float*    V    = proj + 884736;            // 368640
  unsigned* Bph  = (unsigned*)(V + 368640);  // 147456 u32
  unsigned* Sgh  = Bph + 147456;             // 147456 u32
  unsigned* WbP  = Sgh + 147456;             // 1024 u32
  unsigned* pT2  = WbP + 1024;               // 12*768*384 = 3538944 u32
  float*    m_t2 = (float*)(pT2 + 3538944);  // 12*768*48  = 442368
  float*    eout = m_t2 + 442368;            // 1179648
  float*    msm  = eout + 1179648;           // 9216
  float*    linv = msm + 9216;               // 9216
  float*    combX = linv + 9216;             // 768*576 = 442368
  // partial aliases pT2 (dead after k_scav): 11*768*384 = 3244032 <= 3538944
  float* partial = (float*)pT2;

  hipLaunchKernelGGL(k_proj, dim3(384), dim3(288), 0, stream,
                     node, Wqkv, Wvqk, Wvv, proj);
  hipLaunchKernelGGL(k_geom, dim3(36), dim3(256), 0, stream,
                     proj, R, t, Webias, Bph, Sgh, V, WbP);
  hipLaunchKernelGGL(k_fused, dim3(768), dim3(256), 0, stream,
                     edge, WbP, Bph, Sgh, pT2, m_t2, eout, msm, linv);
  hipLaunchKernelGGL(k_scav, dim3(48, 12), dim3(320), 0, stream,
                     pT2, m_t2, msm, linv, V, R, t, combX);
  hipLaunchKernelGGL(k_finalA, dim3(12, 6, 11), dim3(256), 0, stream,
                     eout, combX, Wfin, partial);
  hipLaunchKernelGGL(k_finalB, dim3(288), dim3(256), 0, stream,
                     node, partial, bfin, out);
}

// Round 16
// 226.774 us; speedup vs baseline: 1.0945x; 1.0945x over previous
//
#include <hip/hip_runtime.h>
#include <cmath>

// InvariantPointAttention, N=768, H=12, D=16, NQP=4, NVP=8, NODE=384, EDGE=128.
// R16 = R14 (proven best: 227 us) + s_setprio(1) around k_fused MFMA
// clusters (T5; independent-wave regime per m191). 2-deep prefetch refuted
// twice (R9, R15) -- staging stays 1-register-buffer.

namespace {

constexpr int NN = 768;
constexpr int NH = 12;

constexpr float S3 = 0.5773502691896258f;        // 3^-0.5
constexpr float C1 = 0.25f * S3;
constexpr float C2 = 0.23570226039551584f * S3;
constexpr float C3 = 0.11785113019775792f * S3;

typedef float f32x4 __attribute__((ext_vector_type(4)));
typedef short bf16x8 __attribute__((ext_vector_type(8)));
typedef unsigned int u32x4 __attribute__((ext_vector_type(4)));
typedef unsigned int u32x2 __attribute__((ext_vector_type(2)));
typedef _Float16 f16x2 __attribute__((ext_vector_type(2)));

#define LGKM0 asm volatile("s_waitcnt lgkmcnt(0)" ::: "memory")
#define SCHED0 __builtin_amdgcn_sched_barrier(0)

__device__ inline unsigned cvt_pk_bf16(float lo, float hi) {
  unsigned r;
  asm volatile("v_cvt_pk_bf16_f32 %0, %1, %2" : "=v"(r) : "v"(lo), "v"(hi));
  return r;
}

__device__ inline float fdot2(unsigned a, unsigned b, float c) {
#if __has_builtin(__builtin_amdgcn_fdot2)
  return __builtin_amdgcn_fdot2(__builtin_bit_cast(f16x2, a),
                                __builtin_bit_cast(f16x2, b), c, false);
#else
  union U { unsigned u; _Float16 h[2]; } x, y;
  x.u = a; y.u = b;
  return c + (float)x.h[0] * (float)y.h[0] + (float)x.h[1] * (float)y.h[1];
#endif
}

__device__ inline u32x2 tr_read(unsigned addr) {
  u32x2 d;
  asm volatile("ds_read_b64_tr_b16 %0, %1" : "=v"(d) : "v"(addr));
  return d;
}

__device__ inline f32x4 mfma16(u32x2 a, u32x2 b, f32x4 c) {
  asm volatile("v_mfma_f32_16x16x16_bf16 %0, %1, %2, %0"
               : "+v"(c) : "v"(a), "v"(b));
  return c;
}

__device__ inline unsigned pkf16(float a, float b) {
  union U { _Float16 h[2]; unsigned u; } x;
  x.h[0] = (_Float16)a; x.h[1] = (_Float16)b;
  return x.u;
}

// ---------------------------------------------------------------- k_proj ----
__global__ __launch_bounds__(288) void k_proj(const float* __restrict__ node,
    const float* __restrict__ Wqkv, const float* __restrict__ Wvqk,
    const float* __restrict__ Wvv, float* __restrict__ proj) {
  __shared__ __align__(16) float nl[2][384];
  const int i0 = blockIdx.x * 2;
  const int tid = threadIdx.x;
  for (int idx = tid; idx < 2 * 384; idx += 288)
    ((float*)nl)[idx] = node[(size_t)i0 * 384 + idx];
  __syncthreads();
  const int c0 = tid * 4;
  const float* W; int ld, col;
  if (c0 < 576)      { W = Wqkv; ld = 576; col = c0; }
  else if (c0 < 864) { W = Wvqk; ld = 288; col = c0 - 576; }
  else               { W = Wvv;  ld = 288; col = c0 - 864; }
  float4 acc[2];
#pragma unroll
  for (int r = 0; r < 2; ++r) acc[r] = make_float4(0.f, 0.f, 0.f, 0.f);
#pragma unroll 4
  for (int k = 0; k < 384; ++k) {
    const float4 w4 = *(const float4*)&W[(size_t)k * ld + col];
#pragma unroll
    for (int r = 0; r < 2; ++r) {
      const float nv = nl[r][k];
      acc[r].x += nv * w4.x; acc[r].y += nv * w4.y;
      acc[r].z += nv * w4.z; acc[r].w += nv * w4.w;
    }
  }
#pragma unroll
  for (int r = 0; r < 2; ++r)
    *(float4*)&proj[(size_t)(i0 + r) * 1152 + c0] = acc[r];
}

// ---------------------------------------------------------------- k_geom ----
__global__ __launch_bounds__(256) void k_geom(const float* __restrict__ proj,
    const float* __restrict__ R, const float* __restrict__ t,
    const float* __restrict__ Webias,
    unsigned* __restrict__ Bph, unsigned* __restrict__ Sgh,
    float* __restrict__ V, unsigned* __restrict__ WbP) {
  const int gid = blockIdx.x * 256 + threadIdx.x;
  if (blockIdx.x == 0) {
    const int tid = threadIdx.x;
    const int lane = tid & 63, kk = tid >> 6;
    const int colB = lane & 15, gB = lane >> 4;
    u32x4 wv;
#pragma unroll
    for (int e = 0; e < 4; ++e) {
      const int d = kk * 32 + gB * 8 + 2 * e;
      const float lo = (colB < 12) ? S3 * Webias[d * 12 + colB] : 0.f;
      const float hi = (colB < 12) ? S3 * Webias[(d + 1) * 12 + colB] : 0.f;
      wv[e] = cvt_pk_bf16(lo, hi);
    }
    *(u32x4*)&WbP[(size_t)tid * 4] = wv;
  }
  if (gid >= NN * NH) return;
  const int n = gid / NH, h = gid % NH;
  const float* pr = proj + (size_t)n * 1152;
  const float* Rn = R + n * 9;
  const float t0 = t[n * 3 + 0], t1 = t[n * 3 + 1], t2 = t[n * 3 + 2];
  const size_t hn = (size_t)h * NN + n;
  unsigned* bp = Bph + ((size_t)n * NH + h) * 16;   // j-major
  unsigned* sg = Sgh + ((size_t)n * NH + h) * 16;
#pragma unroll
  for (int m = 0; m < 8; ++m) {
    bp[m] = pkf16(C1 * pr[(12 + h) * 16 + 2 * m], C1 * pr[(12 + h) * 16 + 2 * m + 1]);
    sg[m] = pkf16(pr[h * 16 + 2 * m], pr[h * 16 + 2 * m + 1]);
    V[hn * 40 + 2 * m]     = pr[(24 + h) * 16 + 2 * m];
    V[hn * 40 + 2 * m + 1] = pr[(24 + h) * 16 + 2 * m + 1];
  }
  float gq[12], gk[12];
  float qs = 0.f, ks = 0.f;
#pragma unroll
  for (int p = 0; p < 4; ++p) {
    {
      const float vx = pr[576 + (h * 4 + p) * 3 + 0];
      const float vy = pr[576 + (h * 4 + p) * 3 + 1];
      const float vz = pr[576 + (h * 4 + p) * 3 + 2];
      const float g0 = Rn[0] * vx + Rn[1] * vy + Rn[2] * vz + t0;
      const float g1 = Rn[3] * vx + Rn[4] * vy + Rn[5] * vz + t1;
      const float g2 = Rn[6] * vx + Rn[7] * vy + Rn[8] * vz + t2;
      gq[p * 3 + 0] = g0; gq[p * 3 + 1] = g1; gq[p * 3 + 2] = g2;
      qs += g0 * g0 + g1 * g1 + g2 * g2;
    }
    {
      const float vx = pr[576 + ((12 + h) * 4 + p) * 3 + 0];
      const float vy = pr[576 + ((12 + h) * 4 + p) * 3 + 1];
      const float vz = pr[576 + ((12 + h) * 4 + p) * 3 + 2];
      const float g0 = Rn[0] * vx + Rn[1] * vy + Rn[2] * vz + t0;
      const float g1 = Rn[3] * vx + Rn[4] * vy + Rn[5] * vz + t1;
      const float g2 = Rn[6] * vx + Rn[7] * vy + Rn[8] * vz + t2;
      gk[p * 3 + 0] = g0; gk[p * 3 + 1] = g1; gk[p * 3 + 2] = g2;
      ks += g0 * g0 + g1 * g1 + g2 * g2;
    }
  }
#pragma unroll
  for (int m = 0; m < 6; ++m) {
    bp[8 + m] = pkf16(C2 * gq[2 * m], C2 * gq[2 * m + 1]);
    sg[8 + m] = pkf16(gk[2 * m], gk[2 * m + 1]);
  }
  bp[14] = pkf16(-C3 * qs, 1.0f);
  sg[14] = pkf16(1.0f, -C3 * ks);
  bp[15] = 0u; sg[15] = 0u;
#pragma unroll
  for (int p = 0; p < 8; ++p) {
    const float vx = pr[864 + (h * 8 + p) * 3 + 0];
    const float vy = pr[864 + (h * 8 + p) * 3 + 1];
    const float vz = pr[864 + (h * 8 + p) * 3 + 2];
    V[hn * 40 + 16 + p * 3 + 0] = Rn[0] * vx + Rn[1] * vy + Rn[2] * vz + t0;
    V[hn * 40 + 16 + p * 3 + 1] = Rn[3] * vx + Rn[4] * vy + Rn[5] * vz + t1;
    V[hn * 40 + 16 + p * 3 + 2] = Rn[6] * vx + Rn[7] * vy + Rn[8] * vz + t2;
  }
}

// --------------------------------------------------------------- k_fused ----
// R14 structure: 1-reg-buffer staging, per-wave 4224B LDS slab, decoupled
// fdot2/eb-MFMA; + setprio(1) around MFMA clusters (independent waves).
__global__ __launch_bounds__(256, 3) void k_fused(
    const float* __restrict__ edge, const unsigned* __restrict__ WbP,
    const unsigned* __restrict__ Bph, const unsigned* __restrict__ Sgh,
    unsigned* __restrict__ pT2, float* __restrict__ m_t2,
    float* __restrict__ eout, float* __restrict__ msm,
    float* __restrict__ linv) {
  __shared__ __align__(16) unsigned char wreg[4][4224];   // 16.9 KB total
  const int i = blockIdx.x;
  const int tid = threadIdx.x;
  const int lane = tid & 63;
  const int w = __builtin_amdgcn_readfirstlane(tid >> 6);
  const int g = lane >> 4;          // 0..3
  const int c16 = lane & 15;        // h (logits/C-col), j (eb A-row), d' (PV)
  const int hc = c16 < 12 ? c16 : 11;

  unsigned short* etSw = (unsigned short*)&wreg[w][0];
  const unsigned etbase =
      (unsigned)(uintptr_t)(__attribute__((address_space(3))) unsigned char*)&wreg[w][0];

  bf16x8 wbfrag[4];
#pragma unroll
  for (int kk = 0; kk < 4; ++kk)
    wbfrag[kk] = __builtin_bit_cast(bf16x8,
        *(const u32x4*)&WbP[(size_t)(kk * 64 + lane) * 4]);

  const unsigned* sgp = Sgh + ((size_t)i * NH + hc) * 16;
  const u32x4 sg0 = *(const u32x4*)(sgp + 0);
  const u32x4 sg1 = *(const u32x4*)(sgp + 4);
  const u32x4 sg2 = *(const u32x4*)(sgp + 8);
  const u32x4 sg3 = *(const u32x4*)(sgp + 12);

  float m = -3.0e38f;
  float lsum = 0.f;
  f32x4 acc[8];
#pragma unroll
  for (int dt = 0; dt < 8; ++dt) acc[dt] = (f32x4){0.f, 0.f, 0.f, 0.f};

  float4 ra[8];
  auto load8 = [&](int t) {
    const int jw = t * 64 + w * 16;
#pragma unroll
    for (int q = 0; q < 4; ++q) {
      const int f8 = lane + 64 * q;
      const int j = f8 >> 4, c8 = f8 & 15;
      const float* gp = &edge[((size_t)(i * NN + jw + j)) * 128 + c8 * 8];
      ra[2 * q]     = *(const float4*)gp;
      ra[2 * q + 1] = *(const float4*)(gp + 4);
    }
  };
  auto store8 = [&]() {
#pragma unroll
    for (int q = 0; q < 4; ++q) {
      const int f8 = lane + 64 * q;
      const int j = f8 >> 4, c8 = f8 & 15;
      u32x4 pk;
      pk.x = cvt_pk_bf16(ra[2 * q].x,     ra[2 * q].y);
      pk.y = cvt_pk_bf16(ra[2 * q].z,     ra[2 * q].w);
      pk.z = cvt_pk_bf16(ra[2 * q + 1].x, ra[2 * q + 1].y);
      pk.w = cvt_pk_bf16(ra[2 * q + 1].z, ra[2 * q + 1].w);
      *(u32x4*)&etSw[(c8 >> 1) * 264 + j * 16 + 8 * (c8 & 1)] = pk;
    }
  };

  load8(0);

#pragma unroll 1
  for (int t = 0; t < 12; ++t) {
    const int tw = t * 4 + w;
    LGKM0;                       // prior tile's tr reads drained before overwrite
    store8();                    // compiler waits vmcnt on ra
    SCHED0;
    if (t < 11) load8(t + 1);    // next window flies under compute

    // ---- eb MFMA (feeds logits only at the END -> off the fdot2 path)
    f32x4 ebacc = {0.f, 0.f, 0.f, 0.f};
    __builtin_amdgcn_s_setprio(1);
#pragma unroll
    for (int kk = 0; kk < 4; ++kk) {
      const int dt = 2 * kk + (g >> 1);
      const bf16x8 a = *(const bf16x8*)&etSw[dt * 264 + c16 * 16 + 8 * (g & 1)];
      ebacc = __builtin_amdgcn_mfma_f32_16x16x32_bf16(a, wbfrag[kk], ebacc, 0, 0, 0);
    }
    __builtin_amdgcn_s_setprio(0);

    // ---- logits: fdot2 chain starts from 0 (L2 loads overlap eb MFMAs)
    float lg[4];
#pragma unroll
    for (int r = 0; r < 4; ++r) {
      const unsigned* bpp = Bph + ((size_t)(tw * 16 + 4 * g + r) * NH + hc) * 16;
      const u32x4 b0 = *(const u32x4*)(bpp + 0);
      const u32x4 b1 = *(const u32x4*)(bpp + 4);
      const u32x4 b2 = *(const u32x4*)(bpp + 8);
      const u32x4 b3 = *(const u32x4*)(bpp + 12);
      float a = fdot2(b0.x, sg0.x, 0.f);
      a = fdot2(b0.y, sg0.y, a);
      a = fdot2(b0.z, sg0.z, a); a = fdot2(b0.w, sg0.w, a);
      a = fdot2(b1.x, sg1.x, a); a = fdot2(b1.y, sg1.y, a);
      a = fdot2(b1.z, sg1.z, a); a = fdot2(b1.w, sg1.w, a);
      a = fdot2(b2.x, sg2.x, a); a = fdot2(b2.y, sg2.y, a);
      a = fdot2(b2.z, sg2.z, a); a = fdot2(b2.w, sg2.w, a);
      a = fdot2(b3.x, sg3.x, a); a = fdot2(b3.y, sg3.y, a);
      a = fdot2(b3.z, sg3.z, a);
      lg[r] = a + ebacc[r];
    }

    // ---- defer-max online softmax (per-lane h; m uniform across g-lanes)
    const float lmax = fmaxf(fmaxf(lg[0], lg[1]), fmaxf(lg[2], lg[3]));
    if (__any(lmax > m + 6.f)) {
      float tm = lmax;
      tm = fmaxf(tm, __shfl_xor(tm, 16, 64));
      tm = fmaxf(tm, __shfl_xor(tm, 32, 64));
      const float mn = fmaxf(m, tm);
      const float f = __expf(m - mn);
      m = mn;
      lsum *= f;
      float fr[4];
#pragma unroll
      for (int r = 0; r < 4; ++r) fr[r] = __shfl(f, 4 * g + r, 64);
#pragma unroll
      for (int dt = 0; dt < 8; ++dt) {
        acc[dt][0] *= fr[0]; acc[dt][1] *= fr[1];
        acc[dt][2] *= fr[2]; acc[dt][3] *= fr[3];
      }
    }
    float p0 = __expf(lg[0] - m), p1 = __expf(lg[1] - m);
    float p2 = __expf(lg[2] - m), p3 = __expf(lg[3] - m);
    lsum += (p0 + p1) + (p2 + p3);
    const unsigned pk0 = cvt_pk_bf16(p0, p1);
    const unsigned pk1 = cvt_pk_bf16(p2, p3);
    if (c16 < 12) {
      u32x2 pp; pp.x = pk0; pp.y = pk1;
      *(u32x2*)&pT2[((size_t)c16 * NN + i) * 384 + tw * 8 + g * 2] = pp;
      if (g == 0) m_t2[((size_t)c16 * NN + i) * 48 + tw] = m;
    }

    // ---- PV: A = p in regs; B = E via tr reads, 2 batches of 4
    u32x2 apk; apk.x = pk0; apk.y = pk1;
    u32x2 bfr[4];
#pragma unroll
    for (int half = 0; half < 2; ++half) {
#pragma unroll
      for (int q = 0; q < 4; ++q)
        bfr[q] = tr_read(etbase + (unsigned)((half * 4 + q) * 528 + g * 128 + c16 * 8));
      LGKM0; SCHED0;
      __builtin_amdgcn_s_setprio(1);
#pragma unroll
      for (int q = 0; q < 4; ++q)
        acc[half * 4 + q] = mfma16(apk, bfr[q], acc[half * 4 + q]);
      __builtin_amdgcn_s_setprio(0);
    }
  }

  // ---- tail: write own slab (etS dead after final LGKM0), then merge
  {
    unsigned short* OshW = (unsigned short*)&wreg[w][0];
#pragma unroll
    for (int dt = 0; dt < 8; ++dt) {
      u32x2 pkk;
      pkk.x = cvt_pk_bf16(acc[dt][0], acc[dt][1]);
      pkk.y = cvt_pk_bf16(acc[dt][2], acc[dt][3]);
      *(u32x2*)&OshW[dt * 256 + c16 * 16 + g * 4] = pkk;
    }
    float ls = lsum;
    ls += __shfl_xor(ls, 16, 64);
    ls += __shfl_xor(ls, 32, 64);
    if (lane < 16) {
      *(float*)&wreg[w][4096 + lane * 4] = m;
      *(float*)&wreg[w][4160 + lane * 4] = ls;
    }
  }
  __syncthreads();
  for (int idx = tid; idx < 12 * 128; idx += 256) {
    const int h = idx >> 7, d = idx & 127;
    const int dt = d >> 4, dp = d & 15;
    float mv[4], lv[4], Ov[4];
#pragma unroll
    for (int w2 = 0; w2 < 4; ++w2) {
      mv[w2] = *(const float*)&wreg[w2][4096 + h * 4];
      lv[w2] = *(const float*)&wreg[w2][4160 + h * 4];
      const unsigned short us =
          *(const unsigned short*)&wreg[w2][(dt * 256 + dp * 16 + h) * 2];
      Ov[w2] = __uint_as_float(((unsigned)us) << 16);
    }
    const float mb = fmaxf(fmaxf(mv[0], mv[1]), fmaxf(mv[2], mv[3]));
    const float f0 = __expf(mv[0] - mb), f1 = __expf(mv[1] - mb);
    const float f2 = __expf(mv[2] - mb), f3 = __expf(mv[3] - mb);
    const float lb = lv[0] * f0 + lv[1] * f1 + lv[2] * f2 + lv[3] * f3;
    const float O = Ov[0] * f0 + Ov[1] * f1 + Ov[2] * f2 + Ov[3] * f3;
    eout[(size_t)i * 1536 + h * 128 + d] = O / lb;
    if (d == 0) {
      msm[(size_t)h * NN + i] = mb;
      linv[(size_t)h * NN + i] = 1.0f / lb;
    }
  }
}

// ---------------------------------------------------------------- k_scav ----
__global__ __launch_bounds__(320) void k_scav(const unsigned* __restrict__ pT2,
    const float* __restrict__ m_t2, const float* __restrict__ msm,
    const float* __restrict__ linv, const float* __restrict__ V,
    const float* __restrict__ R, const float* __restrict__ t,
    float* __restrict__ combX) {
  __shared__ __align__(16) float At[64][20];
  __shared__ __align__(16) float Vt[64][40];
  __shared__ __align__(16) float red[320 * 8];
  __shared__ __align__(16) float fac[16][48];
  __shared__ __align__(16) float sc[16][40];
  __shared__ float rinv[16][9];
  __shared__ float tl[16][3];
  const int i0 = blockIdx.x * 16;
  const int h  = blockIdx.y;
  const int tid = threadIdx.x;
  const int js = tid / 80, rem = tid % 80;
  const int rg = rem / 20, cp = rem % 20;

  if (tid < 16) {
    const int i = i0 + tid;
    const float* Rn = R + i * 9;
    const float r00 = Rn[0], r01 = Rn[1], r02 = Rn[2];
    const float r10 = Rn[3], r11 = Rn[4], r12 = Rn[5];
    const float r20 = Rn[6], r21 = Rn[7], r22 = Rn[8];
    const float det = r00 * (r11 * r22 - r12 * r21)
                    - r01 * (r10 * r22 - r12 * r20)
                    + r02 * (r10 * r21 - r11 * r20);
    const float id = 1.0f / det;
    rinv[tid][0] = (r11 * r22 - r12 * r21) * id;
    rinv[tid][1] = (r02 * r21 - r01 * r22) * id;
    rinv[tid][2] = (r01 * r12 - r02 * r11) * id;
    rinv[tid][3] = (r12 * r20 - r10 * r22) * id;
    rinv[tid][4] = (r00 * r22 - r02 * r20) * id;
    rinv[tid][5] = (r02 * r10 - r00 * r12) * id;
    rinv[tid][6] = (r10 * r21 - r11 * r20) * id;
    rinv[tid][7] = (r01 * r20 - r00 * r21) * id;
    rinv[tid][8] = (r00 * r11 - r01 * r10) * id;
    tl[tid][0] = t[i * 3 + 0]; tl[tid][1] = t[i * 3 + 1]; tl[tid][2] = t[i * 3 + 2];
  }
  for (int idx = tid; idx < 768; idx += 320) {
    const int r = idx / 48, tw = idx % 48;
    const size_t hi = (size_t)h * NN + i0 + r;
    fac[r][tw] = __expf(m_t2[hi * 48 + tw] - msm[hi]) * linv[hi];
  }

  float2 a0 = {0.f, 0.f}, a1 = {0.f, 0.f}, a2 = {0.f, 0.f}, a3 = {0.f, 0.f};
  for (int jt = 0; jt < 12; ++jt) {
    __syncthreads();
    for (int idx = tid; idx < 256; idx += 320) {
      const int r = idx >> 4, q = idx & 15;
      const u32x2 v = *(const u32x2*)
          &pT2[((size_t)h * NN + i0 + r) * 384 + jt * 32 + q * 2];
      const float fc = fac[r][jt * 4 + (q >> 2)];
      At[q * 4 + 0][r] = __uint_as_float(v.x << 16) * fc;
      At[q * 4 + 1][r] = __uint_as_float(v.x & 0xffff0000u) * fc;
      At[q * 4 + 2][r] = __uint_as_float(v.y << 16) * fc;
      At[q * 4 + 3][r] = __uint_as_float(v.y & 0xffff0000u) * fc;
    }
    for (int idx = tid; idx < 2560; idx += 320) {
      const int jj = idx / 40, c = idx % 40;
      Vt[jj][c] = V[((size_t)h * NN + jt * 64 + jj) * 40 + c];
    }
    __syncthreads();
#pragma unroll 4
    for (int s = 0; s < 16; ++s) {
      const int jj = js * 16 + s;
      const float4 a4 = *(const float4*)&At[jj][rg * 4];
      const float2 b2 = *(const float2*)&Vt[jj][cp * 2];
      a0.x += a4.x * b2.x; a0.y += a4.x * b2.y;
      a1.x += a4.y * b2.x; a1.y += a4.y * b2.y;
      a2.x += a4.z * b2.x; a2.y += a4.z * b2.y;
      a3.x += a4.w * b2.x; a3.y += a4.w * b2.y;
    }
  }
  __syncthreads();
  *(float4*)&red[tid * 8 + 0] = make_float4(a0.x, a0.y, a1.x, a1.y);
  *(float4*)&red[tid * 8 + 4] = make_float4(a2.x, a2.y, a3.x, a3.y);
  __syncthreads();
  if (tid < 80) {
    const int rg2 = tid / 20, cp2 = tid % 20;
    float4 s0 = make_float4(0.f, 0.f, 0.f, 0.f), s1 = s0;
#pragma unroll
    for (int q = 0; q < 4; ++q) {
      const float4 r0 = *(const float4*)&red[(tid + q * 80) * 8 + 0];
      const float4 r1 = *(const float4*)&red[(tid + q * 80) * 8 + 4];
      s0.x += r0.x; s0.y += r0.y; s0.z += r0.z; s0.w += r0.w;
      s1.x += r1.x; s1.y += r1.y; s1.z += r1.z; s1.w += r1.w;
    }
    sc[rg2 * 4 + 0][cp2 * 2] = s0.x; sc[rg2 * 4 + 0][cp2 * 2 + 1] = s0.y;
    sc[rg2 * 4 + 1][cp2 * 2] = s0.z; sc[rg2 * 4 + 1][cp2 * 2 + 1] = s0.w;
    sc[rg2 * 4 + 2][cp2 * 2] = s1.x; sc[rg2 * 4 + 2][cp2 * 2 + 1] = s1.y;
    sc[rg2 * 4 + 3][cp2 * 2] = s1.z; sc[rg2 * 4 + 3][cp2 * 2 + 1] = s1.w;
  }
  __syncthreads();
  for (int idx = tid; idx < 768; idx += 320) {
    const int r = idx / 48, c = idx % 48;
    const int i = i0 + r;
    float val; int col;
    if (c < 16) {
      val = sc[r][c];
      col = h * 16 + c;
    } else if (c < 40) {
      const int s = c - 16, p = s / 3, x = s % 3;
      const float a0v = sc[r][16 + p * 3 + 0] - tl[r][0];
      const float a1v = sc[r][16 + p * 3 + 1] - tl[r][1];
      const float a2v = sc[r][16 + p * 3 + 2] - tl[r][2];
      val = rinv[r][x * 3 + 0] * a0v + rinv[r][x * 3 + 1] * a1v
          + rinv[r][x * 3 + 2] * a2v;
      col = 192 + h * 24 + s;
    } else {
      const int p = c - 40;
      const float a0v = sc[r][16 + p * 3 + 0] - tl[r][0];
      const float a1v = sc[r][16 + p * 3 + 1] - tl[r][1];
      const float a2v = sc[r][16 + p * 3 + 2] - tl[r][2];
      const float l0 = rinv[r][0] * a0v + rinv[r][1] * a1v + rinv[r][2] * a2v;
      const float l1 = rinv[r][3] * a0v + rinv[r][4] * a1v + rinv[r][5] * a2v;
      const float l2 = rinv[r][6] * a0v + rinv[r][7] * a1v + rinv[r][8] * a2v;
      val = sqrtf(l0 * l0 + l1 * l1 + l2 * l2);
      col = 480 + h * 8 + p;
    }
    combX[(size_t)i * 576 + col] = val;
  }
}

// -------------------------------------------------------------- k_finalA ----
__global__ __launch_bounds__(256) void k_finalA(
    const float* __restrict__ eout, const float* __restrict__ combX,
    const float* __restrict__ Wfin, float* __restrict__ partial) {
  __shared__ __align__(16) float cl[64][36];
  __shared__ __align__(16) float wl[32][68];
  const int i0 = blockIdx.x * 64;
  const int c0 = blockIdx.y * 64;
  const int k0 = blockIdx.z * 192;
  const float* src; int stride, koff;
  if (blockIdx.z < 8) { src = eout;  stride = 1536; koff = k0; }
  else                { src = combX; stride = 576;  koff = k0 - 1536; }
  const int tid = threadIdx.x;
  const int cq = tid & 15, rq = tid >> 4;
  float4 acc[4];
#pragma unroll
  for (int r = 0; r < 4; ++r) acc[r] = make_float4(0.f, 0.f, 0.f, 0.f);
  for (int sub = 0; sub < 6; ++sub) {
    const int kc = sub * 32;
    __syncthreads();
#pragma unroll
    for (int half = 0; half < 2; ++half) {
      const int qi = tid + half * 256;
      const int r = qi >> 3, kq = qi & 7;
      *(float4*)&cl[r][kq * 4] =
          *(const float4*)&src[(size_t)(i0 + r) * stride + koff + kc + kq * 4];
      const int kk = qi >> 4, cc = qi & 15;
      *(float4*)&wl[kk][cc * 4] =
          *(const float4*)&Wfin[(size_t)(k0 + kc + kk) * 384 + c0 + cc * 4];
    }
    __syncthreads();
#pragma unroll
    for (int k4 = 0; k4 < 8; ++k4) {
      float4 a[4], wv[4];
#pragma unroll
      for (int r = 0; r < 4; ++r) a[r] = *(const float4*)&cl[rq * 4 + r][k4 * 4];
#pragma unroll
      for (int q = 0; q < 4; ++q) wv[q] = *(const float4*)&wl[k4 * 4 + q][cq * 4];
#pragma unroll
      for (int r = 0; r < 4; ++r) {
        acc[r].x += a[r].x * wv[0].x + a[r].y * wv[1].x + a[r].z * wv[2].x + a[r].w * wv[3].x;
        acc[r].y += a[r].x * wv[0].y + a[r].y * wv[1].y + a[r].z * wv[2].y + a[r].w * wv[3].y;
        acc[r].z += a[r].x * wv[0].z + a[r].y * wv[1].z + a[r].z * wv[2].z + a[r].w * wv[3].z;
        acc[r].w += a[r].x * wv[0].w + a[r].y * wv[1].w + a[r].z * wv[2].w + a[r].w * wv[3].w;
      }
    }
  }
#pragma unroll
  for (int r = 0; r < 4; ++r)
    *(float4*)&partial[((size_t)blockIdx.z * NN + i0 + rq * 4 + r) * 384 + c0 + cq * 4] = acc[r];
}

// -------------------------------------------------------------- k_finalB ----
__global__ __launch_bounds__(256) void k_finalB(const float* __restrict__ node,
    const float* __restrict__ partial, const float* __restrict__ bfin,
    float* __restrict__ out) {
  const int gid = blockIdx.x * 256 + threadIdx.x;
  const int i = gid / 96, cq = gid % 96;
  float4 v = *(const float4*)&node[(size_t)i * 384 + cq * 4];
  const float4 b = *(const float4*)&bfin[cq * 4];
  v.x += b.x; v.y += b.y; v.z += b.z; v.w += b.w;
#pragma unroll
  for (int s = 0; s < 11; ++s) {
    const float4 p = *(const float4*)&partial[((size_t)s * NN + i) * 384 + cq * 4];
    v.x += p.x; v.y += p.y; v.z += p.z; v.w += p.w;
  }
  *(float4*)&out[(size_t)i * 384 + cq * 4] = v;
}

}  // namespace

extern "C" void kernel_launch(void* const* d_in, const int* in_sizes, int n_in,
                              void* d_out, int out_size, void* d_ws, size_t ws_size,
                              hipStream_t stream) {
  const float* node   = (const float*)d_in[0];
  const float* edge   = (const float*)d_in[1];
  const float* R      = (const float*)d_in[2];
  const float* t      = (const float*)d_in[3];
  const float* Wqkv   = (const float*)d_in[4];
  const float* Wvqk   = (const float*)d_in[5];
  const float* Wvv    = (const float*)d_in[6];
  const float* Webias = (const float*)d_in[7];
  const float* Wfin   = (const float*)d_in[8];
  const float* bfin   = (const float*)d_in[9];
  float* out = (float*)d_out;

  float* ws = (float*)d_ws;
  float*    proj = ws;                       // 884736
  float*    V    = proj + 884736;            // 368640
  unsigned* Bph  = (unsigned*)(V + 368640);  // 147456 u32
  unsigned* Sgh  = Bph + 147456;             // 147456 u32
  unsigned* WbP  = Sgh + 147456;             // 1024 u32
  unsigned* pT2  = WbP + 1024;               // 12*768*384 = 3538944 u32
  float*    m_t2 = (float*)(pT2 + 3538944);  // 12*768*48  = 442368
  float*    eout = m_t2 + 442368;            // 1179648
  float*    msm  = eout + 1179648;           // 9216
  float*    linv = msm + 9216;               // 9216
  float*    combX = linv + 9216;             // 768*576 = 442368
  // partial aliases pT2 (dead after k_scav): 11*768*384 = 3244032 <= 3538944
  float* partial = (float*)pT2;

  hipLaunchKernelGGL(k_proj, dim3(384), dim3(288), 0, stream,
                     node, Wqkv, Wvqk, Wvv, proj);
  hipLaunchKernelGGL(k_geom, dim3(36), dim3(256), 0, stream,
                     proj, R, t, Webias, Bph, Sgh, V, WbP);
  hipLaunchKernelGGL(k_fused, dim3(768), dim3(256), 0, stream,
                     edge, WbP, Bph, Sgh, pT2, m_t2, eout, msm, linv);
  hipLaunchKernelGGL(k_scav, dim3(48, 12), dim3(320), 0, stream,
                     pT2, m_t2, msm, linv, V, R, t, combX);
  hipLaunchKernelGGL(k_finalA, dim3(12, 6, 11), dim3(256), 0, stream,
                     eout, combX, Wfin, partial);
  hipLaunchKernelGGL(k_finalB, dim3(288), dim3(256), 0, stream,
                     node, partial, bfin, out);
}